// Round 3
// baseline (60.102 us; speedup 1.0000x reference)
//
#include <hip/hip_runtime.h>
#include <math.h>

#define SEQ 8192
#define DIM 512  // 2*HIDDEN

typedef float floatx4 __attribute__((ext_vector_type(4)));

// Kernel A: exp_a[i] = expf( sum_d tanhf(e[i][d]) * w[d] )
// One wave (64 lanes) per row; each lane reads 8 contiguous floats (2x float4).
// Max-subtraction is skipped: |a| <= sum|w| (~13 worst case), expf is safely
// in fp32 range, and softmax(a) == softmax(a - m) up to ~ulp.
__global__ __launch_bounds__(256) void ca_exp_a(
    const float* __restrict__ e, const float* __restrict__ w,
    float* __restrict__ exp_a) {
    const int wave = threadIdx.x >> 6;   // 0..3
    const int lane = threadIdx.x & 63;
    const int row  = blockIdx.x * 4 + wave;
    const float* er = e + (size_t)row * DIM + lane * 8;
    const float* wr = w + lane * 8;

    float4 e0 = *reinterpret_cast<const float4*>(er);
    float4 e1 = *reinterpret_cast<const float4*>(er + 4);
    float4 w0 = *reinterpret_cast<const float4*>(wr);
    float4 w1 = *reinterpret_cast<const float4*>(wr + 4);

    float sum = tanhf(e0.x) * w0.x + tanhf(e0.y) * w0.y +
                tanhf(e0.z) * w0.z + tanhf(e0.w) * w0.w +
                tanhf(e1.x) * w1.x + tanhf(e1.y) * w1.y +
                tanhf(e1.z) * w1.z + tanhf(e1.w) * w1.w;

    #pragma unroll
    for (int off = 32; off; off >>= 1) sum += __shfl_down(sum, off, 64);
    if (lane == 0) exp_a[row] = expf(sum);
}

// Kernel C: out[i][j] = exp_a[i] / S, S = sum(exp_a).
// Each block re-reduces exp_a itself (32 KB, L1/L2-hot; identical op order in
// every block -> deterministic, all blocks agree bitwise). 1024 threads handle
// 4 rows; nontemporal 16B stores for the 268 MB streaming output.
__global__ __launch_bounds__(1024) void ca_norm_bcast(
    const float* __restrict__ exp_a, floatx4* __restrict__ out) {
    __shared__ float red[16];
    const int tid = threadIdx.x;

    // Phase 1: block-wide sum of exp_a[0..SEQ). 8192 floats / 1024 threads
    // = 2 float4 per thread.
    const floatx4* ev = reinterpret_cast<const floatx4*>(exp_a);
    floatx4 v0 = ev[tid * 2];
    floatx4 v1 = ev[tid * 2 + 1];
    float s = ((v0.x + v0.y) + (v0.z + v0.w)) +
              ((v1.x + v1.y) + (v1.z + v1.w));
    #pragma unroll
    for (int off = 32; off; off >>= 1) s += __shfl_down(s, off, 64);
    if ((tid & 63) == 0) red[tid >> 6] = s;
    __syncthreads();
    float S = 0.f;
    #pragma unroll
    for (int i = 0; i < 16; ++i) S += red[i];
    const float inv = 1.0f / S;

    // Phase 2: broadcast 4 rows. sub = which row, t = position in row.
    const int sub = tid >> 8;        // 0..3
    const int t   = tid & 255;
    const int row = blockIdx.x * 4 + sub;
    const float p = exp_a[row] * inv;
    floatx4 f;
    f.x = p; f.y = p; f.z = p; f.w = p;
    floatx4* o = out + (size_t)row * (SEQ / 4) + t;
    #pragma unroll
    for (int k = 0; k < 8; ++k)
        __builtin_nontemporal_store(f, o + k * 256);
}

extern "C" void kernel_launch(void* const* d_in, const int* in_sizes, int n_in,
                              void* d_out, int out_size, void* d_ws, size_t ws_size,
                              hipStream_t stream) {
    const float* enc = (const float*)d_in[0];   // [SEQ, DIM] fp32
    const float* w   = (const float*)d_in[1];   // [2*DIM] fp32 (first DIM used)
    // d_in[2] = bias: column-constant, cancels in softmax over axis 0.
    float* out = (float*)d_out;                 // [SEQ, SEQ] fp32

    float* exp_a = (float*)d_ws;                // SEQ floats, fully rewritten each call

    ca_exp_a<<<SEQ / 4, 256, 0, stream>>>(enc, w, exp_a);
    ca_norm_bcast<<<SEQ / 4, 1024, 0, stream>>>(exp_a, (floatx4*)out);
}

// Round 4
// 55.859 us; speedup vs baseline: 1.0760x; 1.0760x over previous
//
#include <hip/hip_runtime.h>
#include <math.h>

#define SEQ 8192
#define DIM 512  // 2*HIDDEN

typedef float floatx4 __attribute__((ext_vector_type(4)));

// Kernel A: exp_a[i] = expf( sum_d tanhf(e[i][d]) * w[d] )
// One wave (64 lanes) per row; each lane reads 8 contiguous floats (2x float4).
// Max-subtraction skipped: |a| <= sum|w| (~13 worst case), expf safely in
// fp32 range; softmax(a) == softmax(a-m) up to ~ulp.
__global__ __launch_bounds__(256) void ca_exp_a(
    const float* __restrict__ e, const float* __restrict__ w,
    float* __restrict__ exp_a) {
    const int wave = threadIdx.x >> 6;   // 0..3
    const int lane = threadIdx.x & 63;
    const int row  = blockIdx.x * 4 + wave;
    const float* er = e + (size_t)row * DIM + lane * 8;
    const float* wr = w + lane * 8;

    float4 e0 = *reinterpret_cast<const float4*>(er);
    float4 e1 = *reinterpret_cast<const float4*>(er + 4);
    float4 w0 = *reinterpret_cast<const float4*>(wr);
    float4 w1 = *reinterpret_cast<const float4*>(wr + 4);

    float sum = tanhf(e0.x) * w0.x + tanhf(e0.y) * w0.y +
                tanhf(e0.z) * w0.z + tanhf(e0.w) * w0.w +
                tanhf(e1.x) * w1.x + tanhf(e1.y) * w1.y +
                tanhf(e1.z) * w1.z + tanhf(e1.w) * w1.w;

    #pragma unroll
    for (int off = 32; off; off >>= 1) sum += __shfl_down(sum, off, 64);
    if (lane == 0) exp_a[row] = expf(sum);
}

// Kernel B: p[i] = exp_a[i] / sum(exp_a). One block; ~2 us.
__global__ __launch_bounds__(1024) void ca_normalize(
    const float* __restrict__ exp_a, float* __restrict__ p) {
    __shared__ float red[16];
    const int tid = threadIdx.x;
    const floatx4* ev = reinterpret_cast<const floatx4*>(exp_a);
    floatx4 v0 = ev[tid * 2];
    floatx4 v1 = ev[tid * 2 + 1];
    float s = ((v0.x + v0.y) + (v0.z + v0.w)) +
              ((v1.x + v1.y) + (v1.z + v1.w));
    #pragma unroll
    for (int off = 32; off; off >>= 1) s += __shfl_down(s, off, 64);
    if ((tid & 63) == 0) red[tid >> 6] = s;
    __syncthreads();
    float S = 0.f;
    #pragma unroll
    for (int i = 0; i < 16; ++i) S += red[i];
    const float inv = 1.0f / S;
    floatx4 o0, o1;
    o0.x = v0.x * inv; o0.y = v0.y * inv; o0.z = v0.z * inv; o0.w = v0.w * inv;
    o1.x = v1.x * inv; o1.y = v1.y * inv; o1.z = v1.z * inv; o1.w = v1.w * inv;
    floatx4* pv = reinterpret_cast<floatx4*>(p);
    pv[tid * 2]     = o0;
    pv[tid * 2 + 1] = o1;
}

// Kernel C: out[i][j] = p[i]. 1024 blocks x 256 threads; 8 rows per block.
// All 8 p-loads issued upfront (uniform -> scalar loads), then 64 coalesced
// plain dwordx4 stores per thread (cached path; output ~LLC-sized).
__global__ __launch_bounds__(256) void ca_bcast(
    const float* __restrict__ p, floatx4* __restrict__ out) {
    const int t = threadIdx.x;
    const int rbase = blockIdx.x * 8;
    float pv[8];
    #pragma unroll
    for (int r = 0; r < 8; ++r) pv[r] = p[rbase + r];
    #pragma unroll
    for (int r = 0; r < 8; ++r) {
        floatx4 f;
        f.x = pv[r]; f.y = pv[r]; f.z = pv[r]; f.w = pv[r];
        floatx4* o = out + (size_t)(rbase + r) * (SEQ / 4) + t;
        #pragma unroll
        for (int k = 0; k < 8; ++k) o[k * 256] = f;
    }
}

extern "C" void kernel_launch(void* const* d_in, const int* in_sizes, int n_in,
                              void* d_out, int out_size, void* d_ws, size_t ws_size,
                              hipStream_t stream) {
    const float* enc = (const float*)d_in[0];   // [SEQ, DIM] fp32
    const float* w   = (const float*)d_in[1];   // [2*DIM] fp32 (first DIM used)
    // d_in[2] = bias: column-constant, cancels in softmax over axis 0.
    float* out = (float*)d_out;                 // [SEQ, SEQ] fp32

    float* exp_a = (float*)d_ws;                // SEQ floats
    float* p     = exp_a + SEQ;                 // SEQ floats

    ca_exp_a<<<SEQ / 4, 256, 0, stream>>>(enc, w, exp_a);
    ca_normalize<<<1, 1024, 0, stream>>>(exp_a, p);
    ca_bcast<<<SEQ / 8, 256, 0, stream>>>(p, (floatx4*)out);
}